// Round 1
// baseline (2518.512 us; speedup 1.0000x reference)
//
#include <hip/hip_runtime.h>
#include <hip/hip_bf16.h>
#include <stdint.h>

// ---------------- problem constants ----------------
#define M_TOK 20736          // B*T = 256*81
#define DIMD  1024
#define TDIM  3072
#define HIDD  4096

#define N_WIN 3145728        // 1024*3072
#define N_W1  4194304        // 4096*1024 (per layer)
#define N_W2  4194304        // 1024*4096 (per layer)
#define N_WZ  1048576
#define N_WM  1024

// quantized-weight element offsets inside qw buffer
#define QWIN  0
#define QW1_0 3145728
#define QW1_1 7340032
#define QW2_0 11534336
#define QW2_1 15728640
#define QWZ   19922944
#define QWM   20971520

// workspace byte offsets (all 256-aligned where it matters)
#define PART_OFF   0          // double[448] stage-1 partial |W| sums
#define SCALES_OFF 4096       // float[8] per-tensor scales
#define QW_OFF     4608       // bf16[20972544] ternary weights
#define HB_OFF     41949696   // bf16 h [M,1024]
#define BIG_OFF    84417024   // bf16: Xc [M,3072], later u [M,4096] (aliased)
// total ws need: ~254.3 MB

typedef __attribute__((ext_vector_type(8))) __bf16 bf16x8;
typedef __attribute__((ext_vector_type(4))) float  f32x4;
typedef __attribute__((ext_vector_type(8))) short  vshort8;
typedef __attribute__((ext_vector_type(4))) short  vshort4;

static __device__ __forceinline__ short f2bf(float f) {   // RNE f32->bf16 bits
    uint32_t u = __builtin_bit_cast(uint32_t, f);
    u = (u + 0x7fffu + ((u >> 16) & 1u)) >> 16;
    return (short)u;
}
static __device__ __forceinline__ float bf2f(short s) {
    uint32_t u = ((uint32_t)(uint16_t)s) << 16;
    return __builtin_bit_cast(float, u);
}
static __device__ __forceinline__ float gelu_f(float v) { // exact (erf) gelu
    return 0.5f * v * (1.0f + erff(v * 0.70710678118654752f));
}

// async global->LDS, 16B per lane; LDS dest is wave-uniform base + lane*16
static __device__ __forceinline__ void gl2lds16(const void* g, void* l) {
    __builtin_amdgcn_global_load_lds(
        (__attribute__((address_space(1))) void*)(g),
        (__attribute__((address_space(3))) void*)(uint32_t)(uintptr_t)(l),
        16, 0, 0);
}

// ------------- stage 1: per-tensor sum(|W|), deterministic -------------
__global__ void abssum_k(const float* __restrict__ w0, const float* __restrict__ w1,
                         const float* __restrict__ w2, const float* __restrict__ w3,
                         const float* __restrict__ w4, const float* __restrict__ w5,
                         const float* __restrict__ w6, double* __restrict__ partial) {
    int seg = blockIdx.x >> 6;
    int chunk = blockIdx.x & 63;
    const float* p; int n;
    switch (seg) {
        case 0: p = w0; n = N_WIN; break;
        case 1: p = w1; n = N_W1;  break;
        case 2: p = w2; n = N_W1;  break;
        case 3: p = w3; n = N_W2;  break;
        case 4: p = w4; n = N_W2;  break;
        case 5: p = w5; n = N_WZ;  break;
        default: p = w6; n = N_WM; break;
    }
    int n4 = n >> 2;
    const float4* src = (const float4*)p;
    double acc = 0.0;
    for (int i = chunk * 256 + threadIdx.x; i < n4; i += 64 * 256) {
        float4 v = src[i];
        acc += (double)fabsf(v.x) + (double)fabsf(v.y) +
               (double)fabsf(v.z) + (double)fabsf(v.w);
    }
    __shared__ double red[256];
    red[threadIdx.x] = acc;
    __syncthreads();
    for (int s = 128; s > 0; s >>= 1) {
        if ((int)threadIdx.x < s) red[threadIdx.x] += red[threadIdx.x + s];
        __syncthreads();
    }
    if (threadIdx.x == 0) partial[blockIdx.x] = red[0];
}

__global__ void finalize_k(const double* __restrict__ partial, float* __restrict__ scales) {
    int t = threadIdx.x;
    if (t < 7) {
        double s = 0.0;
        for (int i = 0; i < 64; i++) s += partial[t * 64 + i];
        const double cnt[7] = {(double)N_WIN, (double)N_W1, (double)N_W1,
                               (double)N_W2, (double)N_W2, (double)N_WZ, (double)N_WM};
        scales[t] = (float)(s / cnt[t]) + 1e-8f;   // mean(|W|) + 1e-8, f32 like jnp
    }
}

// ------------- quantize: ternary = clip(rint(W/a),-1,1) as bf16 -------------
__global__ void quant_k(const float* __restrict__ w0, const float* __restrict__ w1,
                        const float* __restrict__ w2, const float* __restrict__ w3,
                        const float* __restrict__ w4, const float* __restrict__ w5,
                        const float* __restrict__ w6,
                        const float* __restrict__ scales, short* __restrict__ q) {
    const int stride = gridDim.x * blockDim.x;
    const int tid0 = blockIdx.x * blockDim.x + threadIdx.x;
    #pragma unroll 1
    for (int seg = 0; seg < 7; seg++) {
        const float* p; int n; size_t qo;
        switch (seg) {
            case 0: p = w0; n = N_WIN; qo = QWIN;  break;
            case 1: p = w1; n = N_W1;  qo = QW1_0; break;
            case 2: p = w2; n = N_W1;  qo = QW1_1; break;
            case 3: p = w3; n = N_W2;  qo = QW2_0; break;
            case 4: p = w4; n = N_W2;  qo = QW2_1; break;
            case 5: p = w5; n = N_WZ;  qo = QWZ;   break;
            default: p = w6; n = N_WM; qo = QWM;   break;
        }
        const float a = scales[seg];
        const int n4 = n >> 2;
        const float4* src = (const float4*)p;
        short* dst = q + qo;
        for (int i = tid0; i < n4; i += stride) {
            float4 v = src[i];
            float t0 = fminf(1.f, fmaxf(-1.f, rintf(v.x / a)));
            float t1 = fminf(1.f, fmaxf(-1.f, rintf(v.y / a)));
            float t2 = fminf(1.f, fmaxf(-1.f, rintf(v.z / a)));
            float t3 = fminf(1.f, fmaxf(-1.f, rintf(v.w / a)));
            vshort4 o; o[0] = f2bf(t0); o[1] = f2bf(t1); o[2] = f2bf(t2); o[3] = f2bf(t3);
            *(vshort4*)(dst + (size_t)i * 4) = o;
        }
    }
}

// ------------- pack concat([x,y,s_prev]) -> bf16 [M,3072] -------------
__global__ void pack_k(const float* __restrict__ x, const float* __restrict__ y,
                       const float* __restrict__ sp, short* __restrict__ xc) {
    const int NV = M_TOK * 384;   // 8-element groups per row: 3072/8
    const int stride = gridDim.x * blockDim.x;
    for (int v = blockIdx.x * blockDim.x + threadIdx.x; v < NV; v += stride) {
        int row = v / 384;
        int c8 = v - row * 384;
        int seg = c8 >> 7;                    // 0:x 1:y 2:s_prev
        int col = (c8 & 127) << 3;
        const float* src = (seg == 0 ? x : (seg == 1 ? y : sp)) + (size_t)row * DIMD + col;
        float4 a = *(const float4*)src;
        float4 b = *(const float4*)(src + 4);
        vshort8 o;
        o[0] = f2bf(a.x); o[1] = f2bf(a.y); o[2] = f2bf(a.z); o[3] = f2bf(a.w);
        o[4] = f2bf(b.x); o[5] = f2bf(b.y); o[6] = f2bf(b.z); o[7] = f2bf(b.w);
        *(vshort8*)(xc + (size_t)v * 8) = o;
    }
}

// ------------- 128x128-tile bf16 MFMA GEMM, fused epilogues -------------
// A: [M,K] bf16 row-major.  Bw: [N,K] bf16 row-major (weights, K contiguous).
// C[m,n] = (sum_k A[m,k]*Bw[n,k]) * scale + bias[n]  (+variant)
// V=1: write f32+bf16 (proj_in h) | V=2: gelu, write bf16 (u)
// V=3: +resid, write f32+bf16 (h update) | V=4: write f32 (z)
template<int V>
__launch_bounds__(256)
__global__ void gemm_k(const short* __restrict__ A, const short* __restrict__ Bw,
                       const float* __restrict__ bias, const float* __restrict__ scales,
                       int sidx, const float* __restrict__ resid,
                       float* __restrict__ outF, short* __restrict__ outH,
                       int M, int N, int K) {
    __shared__ __align__(16) short lsA[128 * 64];
    __shared__ __align__(16) short lsB[128 * 64];
    const int tid = threadIdx.x;
    const int lane = tid & 63;
    const int w = tid >> 6;          // wave 0..3
    const int wm = w >> 1, wn = w & 1;
    const int bm = blockIdx.x * 128;
    const int bn = blockIdx.y * 128;

    f32x4 acc[4][4];
    const f32x4 z4 = {0.f, 0.f, 0.f, 0.f};
    #pragma unroll
    for (int i = 0; i < 4; i++)
        #pragma unroll
        for (int j = 0; j < 4; j++)
            acc[i][j] = z4;

    // staging: chunk c = i*256+tid covers tile elems [c*8, c*8+8)
    const int srow = tid >> 3;            // 0..31 (plus i*32)
    const int scol = (tid & 7) << 3;      // 0,8,..,56
    const size_t aBase = (size_t)(bm + srow) * K + scol;
    const size_t bBase = (size_t)(bn + srow) * K + scol;

    for (int k0 = 0; k0 < K; k0 += 64) {
        #pragma unroll
        for (int i = 0; i < 4; i++) {
            gl2lds16(A  + aBase + (size_t)(i * 32) * K + k0, &lsA[i * 2048 + w * 512]);
            gl2lds16(Bw + bBase + (size_t)(i * 32) * K + k0, &lsB[i * 2048 + w * 512]);
        }
        __syncthreads();   // drains vmcnt: LDS tiles ready
        #pragma unroll
        for (int kk = 0; kk < 64; kk += 32) {
            bf16x8 af[4], bfr[4];
            #pragma unroll
            for (int mi = 0; mi < 4; mi++)
                af[mi] = *(const bf16x8*)&lsA[(wm * 64 + mi * 16 + (lane & 15)) * 64 + kk + (lane >> 4) * 8];
            #pragma unroll
            for (int ni = 0; ni < 4; ni++)
                bfr[ni] = *(const bf16x8*)&lsB[(wn * 64 + ni * 16 + (lane & 15)) * 64 + kk + (lane >> 4) * 8];
            #pragma unroll
            for (int mi = 0; mi < 4; mi++)
                #pragma unroll
                for (int ni = 0; ni < 4; ni++)
                    acc[mi][ni] = __builtin_amdgcn_mfma_f32_16x16x32_bf16(
                        af[mi], bfr[ni], acc[mi][ni], 0, 0, 0);
        }
        __syncthreads();   // protect LDS before next stage overwrites
    }

    const float s = scales[sidx];
    const int lr = (lane >> 4) * 4;
    const int lc = lane & 15;
    #pragma unroll
    for (int ni = 0; ni < 4; ni++) {
        const int gn = bn + wn * 64 + ni * 16 + lc;
        const float bv = bias[gn];
        #pragma unroll
        for (int mi = 0; mi < 4; mi++) {
            const int gm0 = bm + wm * 64 + mi * 16 + lr;
            #pragma unroll
            for (int j = 0; j < 4; j++) {
                const size_t off = (size_t)(gm0 + j) * N + gn;
                float v = acc[mi][ni][j] * s + bv;
                if (V == 2) {
                    v = gelu_f(v);
                    outH[off] = f2bf(v);
                } else if (V == 1) {
                    outF[off] = v;
                    outH[off] = f2bf(v);
                } else if (V == 3) {
                    v += resid[off];
                    outF[off] = v;
                    outH[off] = f2bf(v);
                } else {
                    outF[off] = v;
                }
            }
        }
    }
}

// ------------- focus mask GEMV: sigmoid(a*(h . t_m) + b_m) -------------
__global__ void focus_k(const float* __restrict__ h, const short* __restrict__ tm,
                        const float* __restrict__ scales, const float* __restrict__ bmp,
                        float* __restrict__ out) {
    const int lane = threadIdx.x & 63;
    const int wid = threadIdx.x >> 6;
    const int m = blockIdx.x * 4 + wid;
    const float* hr = h + (size_t)m * DIMD;
    float dot = 0.f;
    #pragma unroll
    for (int p = 0; p < 4; p++) {
        const int c = p * 256 + lane * 4;
        float4 hv = *(const float4*)(hr + c);
        vshort4 tv = *(const vshort4*)(tm + c);
        dot += hv.x * bf2f(tv[0]) + hv.y * bf2f(tv[1]) +
               hv.z * bf2f(tv[2]) + hv.w * bf2f(tv[3]);
    }
    #pragma unroll
    for (int sft = 32; sft > 0; sft >>= 1) dot += __shfl_down(dot, sft);
    if (lane == 0) {
        float v = scales[6] * dot + bmp[0];
        out[m] = 1.f / (1.f + expf(-v));
    }
}

extern "C" void kernel_launch(void* const* d_in, const int* in_sizes, int n_in,
                              void* d_out, int out_size, void* d_ws, size_t ws_size,
                              hipStream_t stream) {
    (void)in_sizes; (void)n_in; (void)out_size; (void)ws_size;
    const float* x   = (const float*)d_in[0];
    const float* y   = (const float*)d_in[1];
    const float* sp  = (const float*)d_in[2];
    const float* Win = (const float*)d_in[3];
    const float* bin = (const float*)d_in[4];
    const float* W1  = (const float*)d_in[5];
    const float* b1  = (const float*)d_in[6];
    const float* W2  = (const float*)d_in[7];
    const float* b2  = (const float*)d_in[8];
    const float* Wz  = (const float*)d_in[9];
    const float* bz  = (const float*)d_in[10];
    const float* Wm  = (const float*)d_in[11];
    const float* bm  = (const float*)d_in[12];

    char* ws = (char*)d_ws;
    double* partial = (double*)(ws + PART_OFF);
    float* scales   = (float*)(ws + SCALES_OFF);
    short* qw       = (short*)(ws + QW_OFF);
    short* hb       = (short*)(ws + HB_OFF);
    short* big      = (short*)(ws + BIG_OFF);   // Xc, then u (aliased)

    float* out   = (float*)d_out;
    float* hF    = out;                          // h_f32 lives in z region until the end
    float* focus = out + (size_t)M_TOK * DIMD;

    abssum_k<<<dim3(448), dim3(256), 0, stream>>>(
        Win, W1, W1 + (size_t)HIDD * DIMD, W2, W2 + (size_t)DIMD * HIDD, Wz, Wm, partial);
    finalize_k<<<dim3(1), dim3(256), 0, stream>>>(partial, scales);
    quant_k<<<dim3(2048), dim3(256), 0, stream>>>(
        Win, W1, W1 + (size_t)HIDD * DIMD, W2, W2 + (size_t)DIMD * HIDD, Wz, Wm, scales, qw);
    pack_k<<<dim3(2048), dim3(256), 0, stream>>>(x, y, sp, big);

    // proj_in: h = Xc @ Qin^T + b_in
    gemm_k<1><<<dim3(162, 8), dim3(256), 0, stream>>>(
        big, qw + QWIN, bin, scales, 0, nullptr, hF, hb, M_TOK, DIMD, TDIM);
    // layer 0
    gemm_k<2><<<dim3(162, 32), dim3(256), 0, stream>>>(
        hb, qw + QW1_0, b1, scales, 1, nullptr, nullptr, big, M_TOK, HIDD, DIMD);
    gemm_k<3><<<dim3(162, 8), dim3(256), 0, stream>>>(
        big, qw + QW2_0, b2, scales, 3, hF, hF, hb, M_TOK, DIMD, HIDD);
    // layer 1
    gemm_k<2><<<dim3(162, 32), dim3(256), 0, stream>>>(
        hb, qw + QW1_1, b1 + HIDD, scales, 2, nullptr, nullptr, big, M_TOK, HIDD, DIMD);
    gemm_k<3><<<dim3(162, 8), dim3(256), 0, stream>>>(
        big, qw + QW2_1, b2 + DIMD, scales, 4, hF, hF, hb, M_TOK, DIMD, HIDD);
    // focus mask must read h before z overwrites the region
    focus_k<<<dim3(M_TOK / 4), dim3(256), 0, stream>>>(hF, qw + QWM, scales, bm, focus);
    // z = h @ Qz^T + b_z  (overwrites h_f32 region; reads only hb)
    gemm_k<4><<<dim3(162, 8), dim3(256), 0, stream>>>(
        hb, qw + QWZ, bz, scales, 5, nullptr, out, nullptr, M_TOK, DIMD, DIMD);
}